// Round 1
// baseline (173.949 us; speedup 1.0000x reference)
//
#include <hip/hip_runtime.h>

// ChannelAttention on MI355X (gfx950)
// B=128, HW=256 (=16x16), C=1024, S=32, EMB=256, IDF=256(==HW)
//
// out[b,p,c] = sum_s we[b,s,p] * softmax_s( sum_p' wc[b,p',c] * we[b,s,p'] )
// attn[b,c,s] = the softmax probabilities
//
// d_out layout: out (128*16*16*1024 f32) then attn (128*1024*32 f32)
// d_ws: weT[b][p][s]  (B*HW*S f32 = 4 MB), transposed projection so both
// consumers read a contiguous, lane-uniform 128B row per p (scalar loads).

namespace {
constexpr int kB  = 128;
constexpr int kHW = 256;   // IH*IW == IDF
constexpr int kC  = 1024;
constexpr int kS  = 32;
constexpr int kE  = 256;   // EMB
}

// weT[b][p][s] = bias[p] + sum_e emb[b][s][e] * K[e][p]
// grid (4, 128): blockIdx.x = s-quarter (8 s each), blockIdx.y = b; 256 thr (p)
__global__ __launch_bounds__(256) void we_proj_kernel(
    const float* __restrict__ emb, const float* __restrict__ K,
    const float* __restrict__ bias, float* __restrict__ weT) {
  const int b  = blockIdx.y;
  const int sq = blockIdx.x;           // 8 s-values per block
  const int p  = threadIdx.x;
  const float* embb = emb + (size_t)b * kS * kE + (size_t)sq * 8 * kE;

  float acc[8];
#pragma unroll
  for (int j = 0; j < 8; ++j) acc[j] = 0.f;

  for (int e = 0; e < kE; ++e) {
    const float k = K[e * kHW + p];          // lane-coalesced
#pragma unroll
    for (int j = 0; j < 8; ++j)              // embb[...] lane-uniform -> s_load
      acc[j] = fmaf(embb[j * kE + e], k, acc[j]);
  }

  const float bv = bias[p];
  float4* dst = (float4*)(weT + ((size_t)b * kHW + p) * kS + sq * 8);
  dst[0] = make_float4(acc[0] + bv, acc[1] + bv, acc[2] + bv, acc[3] + bv);
  dst[1] = make_float4(acc[4] + bv, acc[5] + bv, acc[6] + bv, acc[7] + bv);
}

// grid (C/256, B), 256 threads: thread owns one channel c.
__global__ __launch_bounds__(256) void attn_kernel(
    const float* __restrict__ wc, const float* __restrict__ weT,
    float* __restrict__ out, float* __restrict__ attn_out) {
  const int b = blockIdx.y;
  const int c = blockIdx.x * 256 + threadIdx.x;
  const float* wcb  = wc  + (size_t)b * kHW * kC;
  const float* weTb = weT + (size_t)b * kHW * kS;

  // ---- Phase A: logits[s] = sum_p wc[p][c] * weT[p][s] ----
  float acc[kS];
#pragma unroll
  for (int s = 0; s < kS; ++s) acc[s] = 0.f;

#pragma unroll 2
  for (int p = 0; p < kHW; ++p) {
    const float w = wcb[p * kC + c];         // lane-coalesced 4B
    const float* wr = weTb + p * kS;         // lane-uniform 128B row
#pragma unroll
    for (int s = 0; s < kS; ++s)
      acc[s] = fmaf(wr[s], w, acc[s]);
  }

  // ---- softmax over s (per-thread, in registers) ----
  float m = acc[0];
#pragma unroll
  for (int s = 1; s < kS; ++s) m = fmaxf(m, acc[s]);
  float sum = 0.f;
#pragma unroll
  for (int s = 0; s < kS; ++s) {
    acc[s] = __expf(acc[s] - m);
    sum += acc[s];
  }
  const float inv = 1.0f / sum;
#pragma unroll
  for (int s = 0; s < kS; ++s) acc[s] *= inv;

  // ---- write attn[b][c][0..31] (contiguous 128B per thread) ----
  float4* ap = (float4*)(attn_out + ((size_t)b * kC + c) * kS);
#pragma unroll
  for (int s4 = 0; s4 < kS / 4; ++s4)
    ap[s4] = make_float4(acc[4 * s4], acc[4 * s4 + 1],
                         acc[4 * s4 + 2], acc[4 * s4 + 3]);

  // ---- Phase B: out[p][c] = sum_s weT[p][s] * prob[s] ----
  float* outb = out + (size_t)b * kHW * kC;
#pragma unroll 2
  for (int p = 0; p < kHW; ++p) {
    const float* wr = weTb + p * kS;         // lane-uniform, scalar-cached
    float o = 0.f;
#pragma unroll
    for (int s = 0; s < kS; ++s)
      o = fmaf(wr[s], acc[s], o);
    outb[p * kC + c] = o;                    // lane-coalesced store
  }
}

extern "C" void kernel_launch(void* const* d_in, const int* in_sizes, int n_in,
                              void* d_out, int out_size, void* d_ws, size_t ws_size,
                              hipStream_t stream) {
  const float* wc   = (const float*)d_in[0];  // [128,16,16,1024]
  const float* emb  = (const float*)d_in[1];  // [128,32,256]
  const float* K    = (const float*)d_in[2];  // [256,256]
  const float* bias = (const float*)d_in[3];  // [256]

  float* out  = (float*)d_out;                         // 33,554,432 f32
  float* attn = out + (size_t)kB * kHW * kC;           // 4,194,304 f32
  float* weT  = (float*)d_ws;                          // 4 MB scratch

  we_proj_kernel<<<dim3(4, kB), 256, 0, stream>>>(emb, K, bias, weT);
  attn_kernel<<<dim3(kC / 256, kB), 256, 0, stream>>>(wc, weT, out, attn);
}